// Round 15
// baseline (127.028 us; speedup 1.0000x reference)
//
#include <hip/hip_runtime.h>

typedef unsigned short u16;
typedef unsigned int u32;
typedef __attribute__((ext_vector_type(8))) short short8;
typedef __attribute__((ext_vector_type(4))) float f32x4;

__device__ __forceinline__ float bf2f(u16 h){ return __builtin_bit_cast(float, ((u32)h) << 16); }
__device__ __forceinline__ u16 f2bf(float f){
  u32 u = __builtin_bit_cast(u32, f);
  u32 r = u + 0x7fffu + ((u >> 16) & 1u);
  return (u16)(r >> 16);
}
// byte offset of channel-octet `co` of tile-pixel `px` in a swizzled [px][256ch] bf16 LDS tile
__device__ __forceinline__ int swzb(int px, int co){
  return px * 512 + ((co * 16) ^ ((((px & 7) ^ ((px >> 3) * 3)) & 7) << 4));
}
__device__ __forceinline__ int fpx(int px){ return ((px & 7) ^ ((px >> 3) * 3)) & 7; }

// ------- Kernel 0b: w1|w2|w3 fp32 [o][c] -> Wh/Wl bf16 hi/lo; block 0 zeros the pad page -------
__global__ __launch_bounds__(256) void wsplit(const float* __restrict__ w1,
                                              const float* __restrict__ w2,
                                              const float* __restrict__ w3,
                                              u16* __restrict__ Wh,
                                              u16* __restrict__ Wl,
                                              u32* __restrict__ zp)
{
  if (blockIdx.x == 0) zp[threadIdx.x] = 0u;    // 1 KB zero page for OOB gload_lds sources
  int i = (blockIdx.x * 256 + threadIdx.x) * 4;
  int z = i >> 16, off = i & 65535;
  const float* w = (z == 0) ? w1 : ((z == 1) ? w2 : w3);
  float4 v = *(const float4*)(w + off);
  u16 h0 = f2bf(v.x), h1 = f2bf(v.y), h2 = f2bf(v.z), h3 = f2bf(v.w);
  u16 l0 = f2bf(v.x - bf2f(h0)), l1 = f2bf(v.y - bf2f(h1));
  u16 l2 = f2bf(v.z - bf2f(h2)), l3 = f2bf(v.w - bf2f(h3));
  uint2 hv; hv.x = (u32)h0 | ((u32)h1 << 16); hv.y = (u32)h2 | ((u32)h3 << 16);
  uint2 lv; lv.x = (u32)l0 | ((u32)l1 << 16); lv.y = (u32)l2 | ((u32)l3 << 16);
  *(uint2*)(Wh + i) = hv;
  *(uint2*)(Wl + i) = lv;
}

// ------- Kernel 1: fused split+qkv, 64-px tiles. grid (256,2,3) = 1536 blocks ->
// 5-6 blocks/CU (was 768 = 3/CU grid-limited): barrier drains overlap across blocks.
// LDS 24 KB; __launch_bounds__(256,5) caps VGPR at 102 (acc[2][4] = 32 VGPR).
// A staged directly from fp32 x on waves 0-1 (R13's verified cq/pq pattern, pair-XOR
// swizzle); B via global_load_lds (R4 pattern). Per-acc MFMA order hh->hl->lh
// unchanged -> bit-identical numerics. -------
__global__ __launch_bounds__(256, 5) void qkv_gemm(const float* __restrict__ x,
                                                   const u16* __restrict__ Wh,
                                                   const u16* __restrict__ Wl,
                                                   u16* __restrict__ qh_, u16* __restrict__ ql_,
                                                   u16* __restrict__ kh_, u16* __restrict__ kl_,
                                                   u16* __restrict__ vo)
{
  __shared__ u16 lAh[64 * 32];
  __shared__ u16 lAl[64 * 32];
  __shared__ u16 lBh[128 * 32];
  __shared__ u16 lBl[128 * 32];
  const int z = blockIdx.z;
  const int t = threadIdx.x;
  const int lane = t & 63, wv = t >> 6;
  const int ln15 = lane & 15, q = lane >> 4;
  const int pix0 = blockIdx.x * 64;
  const int o0 = blockIdx.y * 128;
  const int pw = (wv >> 1) * 32, ow = (wv & 1) * 64;
  const int b = pix0 >> 12, hw0 = pix0 & 4095;
  f32x4 acc[2][4];
  #pragma unroll
  for (int i = 0; i < 2; ++i)
    #pragma unroll
    for (int j = 0; j < 4; ++j)
      acc[i][j] = (f32x4){0.f, 0.f, 0.f, 0.f};

  // ---- B staging geometry (R4-proven; 128 o-rows across 4 waves x 2 slices) ----
  const int Lr = lane >> 2;
  const int cswz = (lane & 3) ^ ((lane >> 3) & 3);
  const int r0 = wv * 32 + Lr;
  const int r1 = wv * 32 + 16 + Lr;
  const int gB0 = z * 65536 + (o0 + r0) * 256 + cswz * 8;
  const int gB1 = z * 65536 + (o0 + r1) * 256 + cswz * 8;
  const int s0 = wv * 1024;
  const int s1 = wv * 1024 + 512;
  const int qsw = (q ^ ((ln15 >> 1) & 3)) * 8;   // B read-side chunk swizzle (u16)

  // ---- A staging geometry: waves 0-1; thread owns (channel-quad cq, pixel-quad pq) ----
  const int cq = (t & 127) >> 4;                 // [0,8): channels 4cq..4cq+3 of K-slice
  const int pq = t & 15;                         // [0,16): pixels 4pq..4pq+3 (64-px tile)
  const int apw = cq ^ (pq & 7);                 // swizzled u32-pair index (write side)
  const float* xb = x + (b * 256) * 4096 + hw0;  // x[(b*256+c)*4096 + hw]
  u32* lAh32 = (u32*)lAh;
  u32* lAl32 = (u32*)lAl;

  for (int kc8 = 0; kc8 < 8; ++kc8) {
    __syncthreads();                    // previous K-step done reading LDS
    // B stage (fire-and-forget; drains at next barrier)
    __builtin_amdgcn_global_load_lds((const u32*)(Wh + gB0 + kc8 * 32), (u32*)(lBh + s0), 16, 0, 0);
    __builtin_amdgcn_global_load_lds((const u32*)(Wh + gB1 + kc8 * 32), (u32*)(lBh + s1), 16, 0, 0);
    if (z < 2) {
      __builtin_amdgcn_global_load_lds((const u32*)(Wl + gB0 + kc8 * 32), (u32*)(lBl + s0), 16, 0, 0);
      __builtin_amdgcn_global_load_lds((const u32*)(Wl + gB1 + kc8 * 32), (u32*)(lBl + s1), 16, 0, 0);
    }
    // A stage (waves 0-1): load fp32 quads, convert hi/lo, b64 write
    if (wv < 2) {
      const float* xk = xb + kc8 * 32 * 4096;
      float4 axv[4];
      #pragma unroll
      for (int jc = 0; jc < 4; ++jc)
        axv[jc] = *(const float4*)(xk + (4 * cq + jc) * 4096 + pq * 4);
      #pragma unroll
      for (int j = 0; j < 4; ++j) {
        const int row = pq * 4 + j;
        const int woff = row * 16 + apw * 2;
        const float v0 = axv[0][j], v1 = axv[1][j], v2 = axv[2][j], v3 = axv[3][j];
        const u16 h0 = f2bf(v0), h1 = f2bf(v1), h2 = f2bf(v2), h3 = f2bf(v3);
        uint2 hw_; hw_.x = (u32)h0 | ((u32)h1 << 16); hw_.y = (u32)h2 | ((u32)h3 << 16);
        *(uint2*)(lAh32 + woff) = hw_;
        if (z < 2) {
          const u16 l0 = f2bf(v0 - bf2f(h0)), l1 = f2bf(v1 - bf2f(h1));
          const u16 l2 = f2bf(v2 - bf2f(h2)), l3 = f2bf(v3 - bf2f(h3));
          uint2 lw_; lw_.x = (u32)l0 | ((u32)l1 << 16); lw_.y = (u32)l2 | ((u32)l3 << 16);
          *(uint2*)(lAl32 + woff) = lw_;
        }
      }
    }
    __syncthreads();                    // tiles visible (gload_lds drained, ds_writes done)
    short8 afh[2], bfh[4];
    #pragma unroll
    for (int i = 0; i < 2; ++i) {
      const int rowA = pw + i * 16 + ln15;
      const int hxr = (rowA >> 2) & 7;
      const int baseA = rowA * 16;
      const uint2 u0 = *(const uint2*)(lAh32 + baseA + ((2 * q) ^ hxr) * 2);
      const uint2 u1 = *(const uint2*)(lAh32 + baseA + ((2 * q + 1) ^ hxr) * 2);
      uint4 uu; uu.x = u0.x; uu.y = u0.y; uu.z = u1.x; uu.w = u1.y;
      afh[i] = __builtin_bit_cast(short8, uu);
    }
    #pragma unroll
    for (int j = 0; j < 4; ++j)
      bfh[j] = *(const short8*)(lBh + (ow + j * 16 + ln15) * 32 + qsw);
    #pragma unroll
    for (int i = 0; i < 2; ++i)
      #pragma unroll
      for (int j = 0; j < 4; ++j)
        acc[i][j] = __builtin_amdgcn_mfma_f32_16x16x32_bf16(afh[i], bfh[j], acc[i][j], 0, 0, 0);
    if (z < 2) {
      // sweep 2a: afh x bfl (rolling bfl fragment)
      #pragma unroll
      for (int j = 0; j < 4; ++j) {
        const short8 bflj = *(const short8*)(lBl + (ow + j * 16 + ln15) * 32 + qsw);
        #pragma unroll
        for (int i = 0; i < 2; ++i)
          acc[i][j] = __builtin_amdgcn_mfma_f32_16x16x32_bf16(afh[i], bflj, acc[i][j], 0, 0, 0);
      }
      // sweep 2b: afl x bfh (rolling afl fragment)
      #pragma unroll
      for (int i = 0; i < 2; ++i) {
        const int rowA = pw + i * 16 + ln15;
        const int hxr = (rowA >> 2) & 7;
        const int baseA = rowA * 16;
        const uint2 u0 = *(const uint2*)(lAl32 + baseA + ((2 * q) ^ hxr) * 2);
        const uint2 u1 = *(const uint2*)(lAl32 + baseA + ((2 * q + 1) ^ hxr) * 2);
        uint4 uu; uu.x = u0.x; uu.y = u0.y; uu.z = u1.x; uu.w = u1.y;
        const short8 afli = __builtin_bit_cast(short8, uu);
        #pragma unroll
        for (int j = 0; j < 4; ++j)
          acc[i][j] = __builtin_amdgcn_mfma_f32_16x16x32_bf16(afli, bfh[j], acc[i][j], 0, 0, 0);
      }
    }
  }

  // D: m(pixel) = pw + i*16 + q*4 + r, n(o) = ow + j*16 + ln15
  if (z == 2) {
    // v: c-major [o][pix]; 4 acc regs = 4 consecutive pixels -> packed uint2 store
    #pragma unroll
    for (int i = 0; i < 2; ++i) {
      int pixb = pix0 + pw + i * 16 + q * 4;
      #pragma unroll
      for (int j = 0; j < 4; ++j) {
        int o = o0 + ow + j * 16 + ln15;
        u32 p0 = (u32)f2bf(acc[i][j][0]) | ((u32)f2bf(acc[i][j][1]) << 16);
        u32 p1 = (u32)f2bf(acc[i][j][2]) | ((u32)f2bf(acc[i][j][3]) << 16);
        uint2 pvv; pvv.x = p0; pvv.y = p1;
        *(uint2*)(vo + o * 16384 + pixb) = pvv;
      }
    }
  } else {
    u16* dsth = (z == 0) ? qh_ : kh_;
    u16* dstl = (z == 0) ? ql_ : kl_;
    #pragma unroll
    for (int i = 0; i < 2; ++i) {
      #pragma unroll
      for (int r = 0; r < 4; ++r) {
        int pix = pix0 + pw + i * 16 + q * 4 + r;
        int ob = o0 + ow + ln15;
        #pragma unroll
        for (int j = 0; j < 4; ++j) {
          float vv = acc[i][j][r];
          u16 hh = f2bf(vv);
          u16 ll = f2bf(vv - bf2f(hh));
          dsth[pix * 256 + ob + j * 16] = hh;
          dstl[pix * 256 + ob + j * 16] = ll;
        }
      }
    }
  }
}

// ------- Kernel 2: banded-MFMA local attention (unchanged from R12/R13). -------
__global__ __launch_bounds__(256, 4) void attn(const u16* __restrict__ qh_,
                                               const u16* __restrict__ ql_,
                                               const u16* __restrict__ kh_,
                                               const u16* __restrict__ kl_,
                                               const u16* __restrict__ vo,
                                               const u16* __restrict__ zp,
                                               float* __restrict__ out)
{
  __shared__ u16 kst[12288];             // 24576 B: k hi @0, k lo @+12288B; q hi@0/lo@+8192B; v @0 (16 KB)
  __shared__ float lg2[2][16][57];       // 7296 B
  __shared__ u16 pb[7][16][40];          // 8960 B   (total 40832 <= 40960 -> 4 blocks/CU)

  const int t = threadIdx.x;
  const int lane = t & 63, wv = t >> 6;
  const int l15 = lane & 15, q4 = lane >> 4;
  const int bid = ((int)blockIdx.x & 7) * 128 + ((int)blockIdx.x >> 3);  // XCD-bijective
  const int quarter = bid & 3;
  const int row = bid >> 2;               // b*64 + h
  const int b = row >> 6, h = row & 63;
  const int wbase = quarter * 16;
  char* sk = (char*)kst;

  for (int i = t; i < 2 * 16 * 57; i += 256) ((float*)lg2)[i] = 0.f;
  for (int i = t; i < 2240; i += 256) ((u32*)pb)[i] = 0u;

  // ---------- q stage: gload_lds, linear dest + inverse-swizzled source ----------
  #pragma unroll
  for (int it = 0; it < 2; ++it) {
    const int px = it * 8 + (t >> 5);
    const int co = (t & 31) ^ fpx(px);
    const int g = (row * 64 + wbase + px) * 256 + co * 8;
    __builtin_amdgcn_global_load_lds((const u32*)(qh_ + g), (u32*)(sk + it * 4096 + wv * 1024), 16, 0, 0);
    __builtin_amdgcn_global_load_lds((const u32*)(ql_ + g), (u32*)(sk + 8192 + it * 4096 + wv * 1024), 16, 0, 0);
  }
  __syncthreads();                       // q landed (vmcnt drained at barrier)

  const int ch = wv >> 1, win = wv & 1;  // wave -> (c-half, n-window)
  // q fragments from LDS (unchanged layout)
  short8 qfh[4], qfl[4];
  #pragma unroll
  for (int u = 0; u < 4; ++u) {
    const int co = (ch * 4 + u) * 4 + q4;
    const int off = swzb(l15, co);
    qfh[u] = *(const short8*)(sk + off);
    qfl[u] = *(const short8*)(sk + 8192 + off);
  }
  __syncthreads();                       // all waves done reading q from sk

  // ---------- phase 1: logits ----------
  const int tidx = win ? (l15 + 12 > 23 ? 23 : l15 + 12) : (l15 - 4 < 0 ? 0 : l15 - 4);
  #pragma unroll 1
  for (int dh = 0; dh < 7; ++dh) {
    const int rdh = h + dh - 3;
    const bool rok = (rdh >= 0) && (rdh < 64);
    const int rp = (b * 64 + (rdh < 0 ? 0 : (rdh > 63 ? 63 : rdh))) * 64;
    // GLOADK(dh): k hi+lo, OOB lanes source the zero page
    #pragma unroll
    for (int it = 0; it < 3; ++it) {
      const int px = it * 8 + (t >> 5);
      const int co = (t & 31) ^ fpx(px);
      const int w = wbase - 4 + px;
      const bool ok = rok && (w >= 0) && (w < 64);
      const int g = (rp + (w < 0 ? 0 : (w > 63 ? 63 : w))) * 256 + co * 8;
      const u16* sh = ok ? kh_ + g : zp;
      const u16* sl = ok ? kl_ + g : zp;
      __builtin_amdgcn_global_load_lds((const u32*)sh, (u32*)(sk + it * 4096 + wv * 1024), 16, 0, 0);
      __builtin_amdgcn_global_load_lds((const u32*)sl, (u32*)(sk + 12288 + it * 4096 + wv * 1024), 16, 0, 0);
    }
    __syncthreads();                     // k landed
    f32x4 a0 = {0.f, 0.f, 0.f, 0.f};
    f32x4 a1 = {0.f, 0.f, 0.f, 0.f};     // split chains for MFMA ILP
    #pragma unroll
    for (int u = 0; u < 4; ++u) {
      const int co = (ch * 4 + u) * 4 + q4;
      const int off = swzb(tidx, co);
      const short8 bh_ = *(const short8*)(sk + off);
      const short8 bl_ = *(const short8*)(sk + 12288 + off);
      a0 = __builtin_amdgcn_mfma_f32_16x16x32_bf16(qfh[u], bh_, a0, 0, 0, 0);
      a1 = __builtin_amdgcn_mfma_f32_16x16x32_bf16(qfh[u], bl_, a1, 0, 0, 0);
      a0 = __builtin_amdgcn_mfma_f32_16x16x32_bf16(qfl[u], bh_, a0, 0, 0, 0);
    }
    // scatter band entries: D col n=l15, row m=q4*4+r; dw = n_w - m_w + 3
    #pragma unroll
    for (int r = 0; r < 4; ++r) {
      const int mloc = q4 * 4 + r;
      const int dw = l15 - mloc - 5 + win * 16;
      if (rok && dw >= 0 && dw < 7) lg2[ch][mloc][dh * 7 + dw] = a0[r] + a1[r];
    }
    __syncthreads();                     // all waves done reading k before next GLOADK
  }

  // ---------- softmax: 16 lanes per pixel (reads lg2/pb only; no sk hazard) ----------
  {
    const int px = t >> 4, sub = t & 15;
    float mx = -3.0e38f;
    for (int i = sub; i < 49; i += 16)
      mx = fmaxf(mx, lg2[0][px][i] + lg2[1][px][i]);
    mx = fmaxf(mx, __shfl_xor(mx, 1));
    mx = fmaxf(mx, __shfl_xor(mx, 2));
    mx = fmaxf(mx, __shfl_xor(mx, 4));
    mx = fmaxf(mx, __shfl_xor(mx, 8));
    float s = 0.f;
    for (int i = sub; i < 49; i += 16) {
      float v = __expf(lg2[0][px][i] + lg2[1][px][i] - mx);
      lg2[0][px][i] = v;                  // stash exp (same-lane RAW only)
      s += v;
    }
    s += __shfl_xor(s, 1);
    s += __shfl_xor(s, 2);
    s += __shfl_xor(s, 4);
    s += __shfl_xor(s, 8);
    const float inv = 1.f / s;
    for (int i = sub; i < 49; i += 16) {
      const int dh7 = i / 7, dw7 = i - dh7 * 7;
      pb[dh7][px][px + 5 + dw7] = f2bf(lg2[0][px][i] * inv);
    }
  }

  // ---------- phase 2: out[c][m'] = sum_n' v[c][n'] * P[m'][n'] ----------
  // v tile [256c][32px], sc-swizzled; staged via gload_lds with inverse-swizzled source.
  f32x4 acc[4];
  #pragma unroll
  for (int i = 0; i < 4; ++i) acc[i] = (f32x4){0.f, 0.f, 0.f, 0.f};
  #pragma unroll 1
  for (int dh = 0; dh < 7; ++dh) {
    const int rdh = h + dh - 3;
    const bool rok2 = (rdh >= 0) && (rdh < 64);
    const int rp = (b * 64 + (rdh < 0 ? 0 : (rdh > 63 ? 63 : rdh))) * 64;
    #pragma unroll
    for (int it = 0; it < 4; ++it) {     // GLOADV(dh)
      const int c = it * 64 + (t >> 2);
      const int sc = (c & 3) ^ ((c >> 2) & 3);
      const int po = (t & 3) ^ sc;
      const int w0 = wbase - 8 + po * 8;
      const bool ok = rok2 && (w0 >= 0) && (w0 <= 56);
      const u16* sv = ok ? vo + c * 16384 + rp + (w0 < 0 ? 0 : (w0 > 56 ? 56 : w0)) : zp;
      __builtin_amdgcn_global_load_lds((const u32*)sv, (u32*)(sk + it * 4096 + wv * 1024), 16, 0, 0);
    }
    __syncthreads();                     // v landed (+ pb visible for dh=0)
    #pragma unroll
    for (int i = 0; i < 4; ++i) {
      const int c = wv * 64 + i * 16 + l15;      // A: m = channel, k-octet = q4
      const int sc = (c & 3) ^ ((c >> 2) & 3);
      const short8 af = *(const short8*)(sk + c * 64 + ((q4 ^ sc) * 16));
      const short8 bf_ = *(const short8*)(&pb[dh][l15][q4 * 8]);
      acc[i] = __builtin_amdgcn_mfma_f32_16x16x32_bf16(af, bf_, acc[i], 0, 0, 0);
    }
    __syncthreads();                     // all waves done reading v before next GLOADV
  }
  #pragma unroll
  for (int i = 0; i < 4; ++i) {
    const int ct = wv * 4 + i;
    // D: row m = channel q4*4+r, col n = pixel l15 -> native [b][c][h][w]
    #pragma unroll
    for (int r = 0; r < 4; ++r)
      out[(b * 256 + ct * 16 + q4 * 4 + r) * 4096 + h * 64 + wbase + l15] = acc[i][r];
  }
}

extern "C" void kernel_launch(void* const* d_in, const int* in_sizes, int n_in,
                              void* d_out, int out_size, void* d_ws, size_t ws_size,
                              hipStream_t stream)
{
  const float* x  = (const float*)d_in[0];
  const float* w1 = (const float*)d_in[1];
  const float* w2 = (const float*)d_in[2];
  const float* w3 = (const float*)d_in[3];
  float* out = (float*)d_out;

  char* ws = (char*)d_ws;
  u16* qh_ = (u16*)ws;                     // 8 MB bf16 hi(q), pixel-major [pix][c]
  u16* ql_ = (u16*)(ws + (8u  << 20));     // 8 MB bf16 lo(q)
  u16* kh_ = (u16*)(ws + (16u << 20));     // 8 MB bf16 hi(k)
  u16* kl_ = (u16*)(ws + (24u << 20));     // 8 MB bf16 lo(k)
  u16* vo  = (u16*)(ws + (32u << 20));     // 8 MB bf16 v, c-major [o][pix]
  u16* Wh  = (u16*)(ws + (40u << 20));     // 384 KB
  u16* Wl  = Wh + 196608;                  // 384 KB
  u32* zp  = (u32*)(ws + (41u << 20));     // 1 KB zero page (zeroed by wsplit)

  wsplit<<<192, 256, 0, stream>>>(w1, w2, w3, Wh, Wl, zp);
  qkv_gemm<<<dim3(256, 2, 3), 256, 0, stream>>>(x, Wh, Wl, qh_, ql_, kh_, kl_, vo);
  attn<<<dim3(1024), 256, 0, stream>>>(qh_, ql_, kh_, kl_, vo, (const u16*)zp, out);
}